// Round 3
// baseline (176.915 us; speedup 1.0000x reference)
//
#include <hip/hip_runtime.h>

// Exact-match lookup of 4M int32 queries in a sorted 8M int32 key table.
// Round 3: packed bucket table, shift=8 (B=2^23 buckets, 16B each, 128 MB).
// Keys within a bucket share bits [30:8], so each 32-bit word is one slot:
//   bits[31:28] flags: 0=empty, 1=valid pair, 2=overflow descriptor (word0)
//   bits[27:8]  value (build verifies 0 <= val < 2^20, else -> overflow)
//   bits[7:0]   low 8 bits of the key
// Overflow bucket (count>4 or value out of 20-bit range):
//   word0 = 2<<28, word1 = start, word2 = end  -> scan keys/vals[start,end).
// Slots filled in sorted order & checked in order -> searchsorted-left
// semantics for duplicates. Queries land in their own bucket, so a low-8-bit
// match implies a full-key match. Build: one pass, each entry written by
// exactly one thread -> deterministic, no atomics, no memset.

constexpr int SENTINEL = (int)0x80000000;  // for the 2-pair fallback format

// ---------------- packed path (shift == 8, needs 128 MB ws) ----------------

__global__ void build_packed_kernel(const int* __restrict__ keys,
                                    const int* __restrict__ vals, int K,
                                    int4* __restrict__ table, unsigned B) {
    int i = blockIdx.x * blockDim.x + threadIdx.x;
    if (i >= K) return;
    unsigned b = ((unsigned)keys[i]) >> 8;

    // first-of-bucket: zero-fill empty buckets before mine
    if (i == 0) {
        for (unsigned e = 0; e < b; ++e) table[e] = make_int4(0, 0, 0, 0);
    } else {
        unsigned bp = ((unsigned)keys[i - 1]) >> 8;
        if (bp != b) {
            for (unsigned e = bp + 1; e < b; ++e) table[e] = make_int4(0, 0, 0, 0);
        }
    }

    unsigned bn = (i + 1 < K) ? (((unsigned)keys[i + 1]) >> 8) : 0xFFFFFFFFu;
    if (bn != b) {  // last-of-bucket: emit the entry
        int first = i;
        while (first > 0 && ((((unsigned)keys[first - 1]) >> 8) == b)) --first;
        int cnt = i - first + 1;
        int w[4] = {0, 0, 0, 0};
        bool ok = (cnt <= 4);
        if (ok) {
            for (int j = 0; j < cnt; ++j) {
                int v = vals[first + j];
                if ((unsigned)v > 0xFFFFFu) { ok = false; break; }
                w[j] = (1 << 28) | (v << 8) | (keys[first + j] & 0xFF);
            }
        }
        int4 e = ok ? make_int4(w[0], w[1], w[2], w[3])
                    : make_int4(2 << 28, first, i + 1, 0);
        table[b] = e;
        if (i == K - 1) {
            for (unsigned t = b + 1; t < B; ++t) table[t] = make_int4(0, 0, 0, 0);
        }
    }
}

__device__ __forceinline__ int resolve_packed(int q, int4 e,
                                              const int* __restrict__ keys,
                                              const int* __restrict__ vals) {
    if ((((unsigned)e.x) >> 28) == 2u) {  // overflow: scan original arrays
        int r = -1;
        for (int j = e.y; j < e.z; ++j) {
            int k = keys[j];
            if (k >= q) { if (k == q) r = vals[j]; break; }
        }
        return r;
    }
    int ql = q & 0xFF;
    int w;
    w = e.x; if ((((unsigned)w) >> 28) == 1u && (w & 0xFF) == ql) return (w >> 8) & 0xFFFFF;
    w = e.y; if ((((unsigned)w) >> 28) == 1u && (w & 0xFF) == ql) return (w >> 8) & 0xFFFFF;
    w = e.z; if ((((unsigned)w) >> 28) == 1u && (w & 0xFF) == ql) return (w >> 8) & 0xFFFFF;
    w = e.w; if ((((unsigned)w) >> 28) == 1u && (w & 0xFF) == ql) return (w >> 8) & 0xFFFFF;
    return -1;
}

__global__ void lookup_packed_kernel(const int* __restrict__ query,
                                     const int* __restrict__ keys,
                                     const int* __restrict__ vals,
                                     const int4* __restrict__ table,
                                     int* __restrict__ out,
                                     int N, unsigned Bmask) {
    int half = (N + 1) >> 1;
    int i = blockIdx.x * blockDim.x + threadIdx.x;
    if (i >= half) return;
    // two independent probe chains per thread for memory-level parallelism
    int i1 = i + half;
    bool has1 = (i1 < N);
    int q0 = query[i];
    int q1 = has1 ? query[i1] : q0;
    int4 e0 = table[(((unsigned)q0) >> 8) & Bmask];
    int4 e1 = table[(((unsigned)q1) >> 8) & Bmask];
    out[i] = resolve_packed(q0, e0, keys, vals);
    if (has1) out[i1] = resolve_packed(q1, e1, keys, vals);
}

// ---------------- fallback: 2-pair full-key entries (any shift) ----------------

__global__ void build_table_kernel(const int* __restrict__ keys,
                                   const int* __restrict__ vals, int K,
                                   int4* __restrict__ table,
                                   int shift, unsigned B) {
    int i = blockIdx.x * blockDim.x + threadIdx.x;
    if (i >= K) return;
    unsigned b  = ((unsigned)keys[i]) >> shift;
    unsigned bn = (i + 1 < K) ? (((unsigned)keys[i + 1]) >> shift) : B;
    if (i == 0) {
        for (unsigned e = 0; e < b; ++e) table[e] = make_int4(0, 0, 0, 0);
    } else {
        unsigned bp = ((unsigned)keys[i - 1]) >> shift;
        if (bp != b) {
            for (unsigned e = bp + 1; e < b; ++e) table[e] = make_int4(0, 0, 0, 0);
        }
    }
    if (bn != b) {
        int first = i;
        while (first > 0 && (((unsigned)keys[first - 1]) >> shift) == b) --first;
        int cnt = i - first + 1;
        int4 e;
        if (cnt == 1)      e = make_int4(keys[i], vals[i], 0, 0);
        else if (cnt == 2) e = make_int4(keys[first], vals[first], keys[i], vals[i]);
        else               e = make_int4(SENTINEL, first, i + 1, 0);
        table[b] = e;
        if (i == K - 1) {
            for (unsigned t = b + 1; t < B; ++t) table[t] = make_int4(0, 0, 0, 0);
        }
    }
}

__global__ void lookup16_kernel(const int* __restrict__ query,
                                const int* __restrict__ keys,
                                const int* __restrict__ vals,
                                const int4* __restrict__ table,
                                int* __restrict__ out,
                                int N, int shift, unsigned Bmask) {
    int i = blockIdx.x * blockDim.x + threadIdx.x;
    if (i >= N) return;
    int q = query[i];
    int4 e = table[(((unsigned)q) >> shift) & Bmask];
    int r;
    if (e.x == q) {
        r = e.y;
    } else if (e.x == SENTINEL) {
        r = -1;
        for (int j = e.y; j < e.z; ++j) {
            int k = keys[j];
            if (k >= q) { if (k == q) r = vals[j]; break; }
        }
    } else if (e.z == q) {
        r = e.w;
    } else {
        r = -1;
    }
    out[i] = r;
}

__global__ void lookup_bsearch_kernel(const int* __restrict__ query,
                                      const int* __restrict__ keys,
                                      const int* __restrict__ vals,
                                      int* __restrict__ out,
                                      int N, int K) {
    int i = blockIdx.x * blockDim.x + threadIdx.x;
    if (i >= N) return;
    int q = query[i];
    int lo = 0, hi = K;
    while (lo < hi) {
        int mid = (lo + hi) >> 1;
        if (keys[mid] < q) lo = mid + 1; else hi = mid;
    }
    int r = -1;
    if (lo < K && keys[lo] == q) r = vals[lo];
    out[i] = r;
}

extern "C" void kernel_launch(void* const* d_in, const int* in_sizes, int n_in,
                              void* d_out, int out_size, void* d_ws, size_t ws_size,
                              hipStream_t stream) {
    const int* query = (const int*)d_in[0];
    const int* keys  = (const int*)d_in[1];
    const int* vals  = (const int*)d_in[2];
    int* out = (int*)d_out;
    const int N = in_sizes[0];
    const int K = in_sizes[1];
    const int tb = 256;

    if (((size_t)16 << 23) <= ws_size) {
        // packed path: B = 2^23 buckets, shift 8, 128 MB
        unsigned B = 1u << 23;
        int4* table = (int4*)d_ws;
        build_packed_kernel<<<(K + tb - 1) / tb, tb, 0, stream>>>(keys, vals, K,
                                                                  table, B);
        int half = (N + 1) >> 1;
        lookup_packed_kernel<<<(half + tb - 1) / tb, tb, 0, stream>>>(
            query, keys, vals, table, out, N, B - 1);
    } else {
        int logB = 22;
        while (logB > 18 && ((size_t)16 << logB) > ws_size) logB--;
        if (((size_t)16 << logB) <= ws_size) {
            unsigned B = 1u << logB;
            int shift = 31 - logB;
            int4* table = (int4*)d_ws;
            build_table_kernel<<<(K + tb - 1) / tb, tb, 0, stream>>>(keys, vals, K,
                                                                     table, shift, B);
            lookup16_kernel<<<(N + tb - 1) / tb, tb, 0, stream>>>(query, keys, vals,
                                                                  table, out, N,
                                                                  shift, B - 1);
        } else {
            lookup_bsearch_kernel<<<(N + tb - 1) / tb, tb, 0, stream>>>(query, keys,
                                                                        vals, out, N, K);
        }
    }
}